// Round 2
// baseline (655.534 us; speedup 1.0000x reference)
//
#include <hip/hip_runtime.h>
#include <math.h>

#define N_NODES 100000
#define N_EDGES 1600000
#define IN_DIM 128
#define OUT_DIM 64

// K1: Wh = h @ W.T, 16 nodes per block. Each 64-lane wave computes 4 nodes
// (lane == output dim), sharing each Ws[d][k] read across the 4 accumulators.
// Also produces per-node attention scalars s1[n]=Wh[n]·a_w[0:64],
// s2[n]=Wh[n]·a_w[64:128] via wave shuffle-reduce.
__global__ __launch_bounds__(256) void k_wh(const float* __restrict__ h,
                                            const float* __restrict__ W,
                                            const float* __restrict__ a_w,
                                            float* __restrict__ Wh,
                                            float* __restrict__ s1,
                                            float* __restrict__ s2) {
    __shared__ float Ws[OUT_DIM][IN_DIM + 1];   // pad -> (d+k)%32 banks, 2-way = free
    __shared__ float hs[16][IN_DIM];            // 8 KB
    const int tid = threadIdx.x;
    for (int i = tid; i < OUT_DIM * IN_DIM; i += 256)
        Ws[i >> 7][i & 127] = W[i];
    const int node0 = blockIdx.x * 16;
    for (int i = tid; i < 16 * IN_DIM; i += 256) {
        int n = node0 + (i >> 7);
        hs[i >> 7][i & 127] = (n < N_NODES) ? h[(size_t)n * IN_DIM + (i & 127)] : 0.f;
    }
    __syncthreads();
    const int local0 = (tid >> 6) * 4;  // wave's first node within block
    const int d = tid & 63;             // output dim == lane
    float acc[4] = {0.f, 0.f, 0.f, 0.f};
    for (int k = 0; k < IN_DIM; ++k) {
        float w = Ws[d][k];
        #pragma unroll
        for (int j = 0; j < 4; ++j)
            acc[j] = fmaf(hs[local0 + j][k], w, acc[j]);
    }
    const float aw1 = a_w[d], aw2 = a_w[64 + d];
    #pragma unroll
    for (int j = 0; j < 4; ++j) {
        int n = node0 + local0 + j;
        float v1 = acc[j] * aw1;
        float v2 = acc[j] * aw2;
        #pragma unroll
        for (int off = 32; off > 0; off >>= 1) {
            v1 += __shfl_xor(v1, off, 64);
            v2 += __shfl_xor(v2, off, 64);
        }
        if (n < N_NODES) {
            Wh[(size_t)n * OUT_DIM + d] = acc[j];
            if (d == 0) { s1[n] = v1; s2[n] = v2; }
        }
    }
}

// K2: histogram of destination nodes (int atomics into a 400 KB table).
__global__ __launch_bounds__(256) void k_hist(const int* __restrict__ dst,
                                              int* __restrict__ count) {
    int e = blockIdx.x * 256 + threadIdx.x;
    if (e < N_EDGES) atomicAdd(&count[dst[e]], 1);
}

// K3: single-block exclusive scan of count -> offsets (+ copy to cursor).
__global__ __launch_bounds__(256) void k_scan(const int* __restrict__ count,
                                              int* __restrict__ offsets,
                                              int* __restrict__ cursor) {
    __shared__ int ssum[256];
    const int tid = threadIdx.x;
    const int CHUNK = (N_NODES + 255) / 256;    // 391
    const int begin = tid * CHUNK;
    const int end = min(begin + CHUNK, N_NODES);
    int local = 0;
    for (int i = begin; i < end; ++i) local += count[i];
    ssum[tid] = local;
    __syncthreads();
    if (tid == 0) {
        int run = 0;
        for (int i = 0; i < 256; ++i) { int v = ssum[i]; ssum[i] = run; run += v; }
    }
    __syncthreads();
    int run = ssum[tid];
    for (int i = begin; i < end; ++i) {
        int v = count[i];
        offsets[i] = run;
        cursor[i]  = run;
        run += v;
    }
    if (tid == 255) offsets[N_NODES] = run;     // == N_EDGES
}

// K4: scatter edges into dst-sorted order (permutation via cursor atomics).
__global__ __launch_bounds__(256) void k_scatter(const int* __restrict__ ei,
                                                 int* __restrict__ cursor,
                                                 int* __restrict__ srcs_sorted,
                                                 int* __restrict__ eid_sorted) {
    int e = blockIdx.x * 256 + threadIdx.x;
    if (e >= N_EDGES) return;
    int src = ei[e];
    int dst = ei[N_EDGES + e];
    int pos = atomicAdd(&cursor[dst], 1);
    srcs_sorted[pos] = src;
    eid_sorted[pos]  = e;
}

// K5: one 64-lane wave per dst node; lane == output dim. Segment-reduce the
// sorted edge list in registers: no atomics anywhere. Division by the segment
// sum distributes, so alpha_sum is just the register S. ELU fused.
__global__ __launch_bounds__(256) void k_agg(const int* __restrict__ srcs_sorted,
                                             const int* __restrict__ eid_sorted,
                                             const int* __restrict__ offsets,
                                             const float* __restrict__ Wh,
                                             const float* __restrict__ s1,
                                             const float* __restrict__ s2,
                                             float* __restrict__ out,
                                             float* __restrict__ alpha_norm) {
    int gid = blockIdx.x * 256 + threadIdx.x;
    int node = gid >> 6;
    int d = gid & 63;
    if (node >= N_NODES) return;
    const int beg = offsets[node];
    const int end = offsets[node + 1];
    const float s2v = s2[node];
    float acc = 0.f, S = 0.f;
    for (int i = beg; i < end; ++i) {
        int src = srcs_sorted[i];               // uniform across wave -> broadcast
        float a = s1[src] + s2v;
        a = (a > 0.f) ? a : 0.2f * a;           // leaky_relu(0.2)
        float ae = expf(a);
        S += ae;
        acc = fmaf(ae, Wh[(size_t)src * OUT_DIM + d], acc);  // 256B coalesced row
    }
    const float inv = 1.f / (S + 1e-9f);
    float o = acc * inv;
    out[(size_t)node * OUT_DIM + d] = (o > 0.f) ? o : expf(o) - 1.f;
    // lane-parallel alpha_norm writes back to ORIGINAL edge order
    for (int i = beg + d; i < end; i += 64) {
        int src = srcs_sorted[i];
        float a = s1[src] + s2v;
        a = (a > 0.f) ? a : 0.2f * a;
        alpha_norm[eid_sorted[i]] = expf(a) * inv;
    }
}

extern "C" void kernel_launch(void* const* d_in, const int* in_sizes, int n_in,
                              void* d_out, int out_size, void* d_ws, size_t ws_size,
                              hipStream_t stream) {
    const float* h   = (const float*)d_in[0];
    const float* W   = (const float*)d_in[1];
    const float* a_w = (const float*)d_in[2];
    const int*   ei  = (const int*)d_in[3];    // [2, E]: row0=src, row1=dst

    float* out        = (float*)d_out;                       // [N, 64] elu(out)
    float* alpha_norm = out + (size_t)N_NODES * OUT_DIM;     // [E]

    // workspace layout (~40.4 MB)
    char* ws = (char*)d_ws;
    float* Wh          = (float*)ws;  ws += (size_t)N_NODES * OUT_DIM * 4;
    float* s1          = (float*)ws;  ws += (size_t)N_NODES * 4;
    float* s2          = (float*)ws;  ws += (size_t)N_NODES * 4;
    int*   count       = (int*)ws;    ws += (size_t)N_NODES * 4;
    int*   offsets     = (int*)ws;    ws += (size_t)(N_NODES + 1) * 4;
    int*   cursor      = (int*)ws;    ws += (size_t)N_NODES * 4;
    int*   srcs_sorted = (int*)ws;    ws += (size_t)N_EDGES * 4;
    int*   eid_sorted  = (int*)ws;    ws += (size_t)N_EDGES * 4;

    hipMemsetAsync(count, 0, (size_t)N_NODES * 4, stream);

    k_wh<<<(N_NODES + 15) / 16, 256, 0, stream>>>(h, W, a_w, Wh, s1, s2);
    k_hist<<<(N_EDGES + 255) / 256, 256, 0, stream>>>(ei + N_EDGES, count);
    k_scan<<<1, 256, 0, stream>>>(count, offsets, cursor);
    k_scatter<<<(N_EDGES + 255) / 256, 256, 0, stream>>>(ei, cursor, srcs_sorted, eid_sorted);
    k_agg<<<(N_NODES * 64 + 255) / 256, 256, 0, stream>>>(srcs_sorted, eid_sorted, offsets,
                                                          Wh, s1, s2, out, alpha_norm);
}

// Round 3
// 438.743 us; speedup vs baseline: 1.4941x; 1.4941x over previous
//
#include <hip/hip_runtime.h>
#include <math.h>

#define N_NODES 100000
#define N_EDGES 1600000
#define IN_DIM 128
#define OUT_DIM 64

#define SCAN_ITEMS 1024                       // per block in the 3-phase scan
#define SCAN_NB ((N_NODES + SCAN_ITEMS - 1) / SCAN_ITEMS)   // 98

// K1: Wh = h @ W.T, 16 nodes per block. Each 64-lane wave computes 4 nodes
// (lane == output dim), sharing each Ws[d][k] read across the 4 accumulators.
// Also per-node attention scalars s1[n]=Wh[n]·a_w[0:64], s2[n]=Wh[n]·a_w[64:128].
__global__ __launch_bounds__(256) void k_wh(const float* __restrict__ h,
                                            const float* __restrict__ W,
                                            const float* __restrict__ a_w,
                                            float* __restrict__ Wh,
                                            float* __restrict__ s1,
                                            float* __restrict__ s2) {
    __shared__ float Ws[OUT_DIM][IN_DIM + 1];   // pad: 2-way bank alias = free
    __shared__ float hs[16][IN_DIM];
    const int tid = threadIdx.x;
    for (int i = tid; i < OUT_DIM * IN_DIM; i += 256)
        Ws[i >> 7][i & 127] = W[i];
    const int node0 = blockIdx.x * 16;
    for (int i = tid; i < 16 * IN_DIM; i += 256) {
        int n = node0 + (i >> 7);
        hs[i >> 7][i & 127] = (n < N_NODES) ? h[(size_t)n * IN_DIM + (i & 127)] : 0.f;
    }
    __syncthreads();
    const int local0 = (tid >> 6) * 4;
    const int d = tid & 63;
    float acc[4] = {0.f, 0.f, 0.f, 0.f};
    for (int k = 0; k < IN_DIM; ++k) {
        float w = Ws[d][k];
        #pragma unroll
        for (int j = 0; j < 4; ++j)
            acc[j] = fmaf(hs[local0 + j][k], w, acc[j]);
    }
    const float aw1 = a_w[d], aw2 = a_w[64 + d];
    #pragma unroll
    for (int j = 0; j < 4; ++j) {
        int n = node0 + local0 + j;
        float v1 = acc[j] * aw1;
        float v2 = acc[j] * aw2;
        #pragma unroll
        for (int off = 32; off > 0; off >>= 1) {
            v1 += __shfl_xor(v1, off, 64);
            v2 += __shfl_xor(v2, off, 64);
        }
        if (n < N_NODES) {
            Wh[(size_t)n * OUT_DIM + d] = acc[j];
            if (d == 0) { s1[n] = v1; s2[n] = v2; }
        }
    }
}

// K2: histogram of destination nodes (int atomics into a 400 KB L2-resident table).
__global__ __launch_bounds__(256) void k_hist(const int* __restrict__ dst,
                                              int* __restrict__ count) {
    int e = blockIdx.x * 256 + threadIdx.x;
    if (e < N_EDGES) atomicAdd(&count[dst[e]], 1);
}

// K3a: per-block partial sums of count (1024 elements / block).
__global__ __launch_bounds__(256) void k_scan_part(const int* __restrict__ count,
                                                   int* __restrict__ bsum) {
    __shared__ int wsum[4];
    const int tid = threadIdx.x;
    const int base = blockIdx.x * SCAN_ITEMS + tid * 4;
    int s = 0;
    #pragma unroll
    for (int j = 0; j < 4; ++j) {
        int i = base + j;
        if (i < N_NODES) s += count[i];
    }
    #pragma unroll
    for (int off = 32; off > 0; off >>= 1) s += __shfl_xor(s, off, 64);
    if ((tid & 63) == 0) wsum[tid >> 6] = s;
    __syncthreads();
    if (tid == 0) bsum[blockIdx.x] = wsum[0] + wsum[1] + wsum[2] + wsum[3];
}

// K3b: tiny single-block exclusive scan of the 98 block sums.
__global__ __launch_bounds__(128) void k_scan_mid(int* __restrict__ bsum) {
    __shared__ int s[SCAN_NB];
    const int tid = threadIdx.x;
    if (tid < SCAN_NB) s[tid] = bsum[tid];
    __syncthreads();
    if (tid == 0) {
        int run = 0;
        for (int i = 0; i < SCAN_NB; ++i) { int v = s[i]; s[i] = run; run += v; }
    }
    __syncthreads();
    if (tid < SCAN_NB) bsum[tid] = s[tid];
}

// K3c: block-local exclusive scan + block base -> offsets & cursor.
__global__ __launch_bounds__(256) void k_scan_final(const int* __restrict__ count,
                                                    const int* __restrict__ bsum,
                                                    int* __restrict__ offsets,
                                                    int* __restrict__ cursor) {
    __shared__ int wtot[4];
    const int tid = threadIdx.x;
    const int lane = tid & 63;
    const int wid = tid >> 6;
    const int base = blockIdx.x * SCAN_ITEMS + tid * 4;
    int c[4];
    #pragma unroll
    for (int j = 0; j < 4; ++j)
        c[j] = (base + j < N_NODES) ? count[base + j] : 0;
    int tot = c[0] + c[1] + c[2] + c[3];
    // wave-level inclusive scan of per-thread totals
    int inc = tot;
    #pragma unroll
    for (int off = 1; off < 64; off <<= 1) {
        int u = __shfl_up(inc, off, 64);
        if (lane >= off) inc += u;
    }
    if (lane == 63) wtot[wid] = inc;
    __syncthreads();
    int wbase = 0;
    #pragma unroll
    for (int w = 0; w < 4; ++w) wbase += (w < wid) ? wtot[w] : 0;
    int run = bsum[blockIdx.x] + wbase + (inc - tot);   // exclusive prefix
    #pragma unroll
    for (int j = 0; j < 4; ++j) {
        int i = base + j;
        if (i < N_NODES) { offsets[i] = run; cursor[i] = run; run += c[j]; }
    }
    if (blockIdx.x == 0 && tid == 0) offsets[N_NODES] = N_EDGES;
}

// K4: scatter edges into dst-sorted order (permutation via cursor atomics).
__global__ __launch_bounds__(256) void k_scatter(const int* __restrict__ ei,
                                                 int* __restrict__ cursor,
                                                 int* __restrict__ srcs_sorted,
                                                 int* __restrict__ eid_sorted) {
    int e = blockIdx.x * 256 + threadIdx.x;
    if (e >= N_EDGES) return;
    int src = ei[e];
    int dst = ei[N_EDGES + e];
    int pos = atomicAdd(&cursor[dst], 1);
    srcs_sorted[pos] = src;
    eid_sorted[pos]  = e;
}

// K5: one 64-lane wave per dst node; lane == output dim. Segment-reduce in
// registers, no atomics. ELU fused; alpha_norm written in original edge order.
__global__ __launch_bounds__(256) void k_agg(const int* __restrict__ srcs_sorted,
                                             const int* __restrict__ eid_sorted,
                                             const int* __restrict__ offsets,
                                             const float* __restrict__ Wh,
                                             const float* __restrict__ s1,
                                             const float* __restrict__ s2,
                                             float* __restrict__ out,
                                             float* __restrict__ alpha_norm) {
    int gid = blockIdx.x * 256 + threadIdx.x;
    int node = gid >> 6;
    int d = gid & 63;
    if (node >= N_NODES) return;
    const int beg = offsets[node];
    const int end = offsets[node + 1];
    const float s2v = s2[node];
    float acc = 0.f, S = 0.f;
    for (int i = beg; i < end; ++i) {
        int src = srcs_sorted[i];               // wave-uniform -> broadcast
        float a = s1[src] + s2v;
        a = (a > 0.f) ? a : 0.2f * a;           // leaky_relu(0.2)
        float ae = expf(a);
        S += ae;
        acc = fmaf(ae, Wh[(size_t)src * OUT_DIM + d], acc);  // 256B coalesced row
    }
    const float inv = 1.f / (S + 1e-9f);
    float o = acc * inv;
    out[(size_t)node * OUT_DIM + d] = (o > 0.f) ? o : expf(o) - 1.f;
    for (int i = beg + d; i < end; i += 64) {
        int src = srcs_sorted[i];
        float a = s1[src] + s2v;
        a = (a > 0.f) ? a : 0.2f * a;
        alpha_norm[eid_sorted[i]] = expf(a) * inv;
    }
}

extern "C" void kernel_launch(void* const* d_in, const int* in_sizes, int n_in,
                              void* d_out, int out_size, void* d_ws, size_t ws_size,
                              hipStream_t stream) {
    const float* h   = (const float*)d_in[0];
    const float* W   = (const float*)d_in[1];
    const float* a_w = (const float*)d_in[2];
    const int*   ei  = (const int*)d_in[3];    // [2, E]: row0=src, row1=dst

    float* out        = (float*)d_out;                       // [N, 64] elu(out)
    float* alpha_norm = out + (size_t)N_NODES * OUT_DIM;     // [E]

    // workspace layout (~40.4 MB)
    char* ws = (char*)d_ws;
    float* Wh          = (float*)ws;  ws += (size_t)N_NODES * OUT_DIM * 4;
    float* s1          = (float*)ws;  ws += (size_t)N_NODES * 4;
    float* s2          = (float*)ws;  ws += (size_t)N_NODES * 4;
    int*   count       = (int*)ws;    ws += (size_t)N_NODES * 4;
    int*   offsets     = (int*)ws;    ws += (size_t)(N_NODES + 1) * 4;
    int*   cursor      = (int*)ws;    ws += (size_t)N_NODES * 4;
    int*   bsum        = (int*)ws;    ws += (size_t)SCAN_NB * 4;
    int*   srcs_sorted = (int*)ws;    ws += (size_t)N_EDGES * 4;
    int*   eid_sorted  = (int*)ws;    ws += (size_t)N_EDGES * 4;

    hipMemsetAsync(count, 0, (size_t)N_NODES * 4, stream);

    k_wh<<<(N_NODES + 15) / 16, 256, 0, stream>>>(h, W, a_w, Wh, s1, s2);
    k_hist<<<(N_EDGES + 255) / 256, 256, 0, stream>>>(ei + N_EDGES, count);
    k_scan_part<<<SCAN_NB, 256, 0, stream>>>(count, bsum);
    k_scan_mid<<<1, 128, 0, stream>>>(bsum);
    k_scan_final<<<SCAN_NB, 256, 0, stream>>>(count, bsum, offsets, cursor);
    k_scatter<<<(N_EDGES + 255) / 256, 256, 0, stream>>>(ei, cursor, srcs_sorted, eid_sorted);
    k_agg<<<(N_NODES * 64 + 255) / 256, 256, 0, stream>>>(srcs_sorted, eid_sorted, offsets,
                                                          Wh, s1, s2, out, alpha_norm);
}

// Round 4
// 336.433 us; speedup vs baseline: 1.9485x; 1.3041x over previous
//
#include <hip/hip_runtime.h>
#include <hip/hip_bf16.h>
#include <math.h>

#define N_NODES 100000
#define N_EDGES 1600000
#define IN_DIM 128
#define OUT_DIM 64

#define SCAN_ITEMS 1024                       // per block in the 3-phase scan
#define SCAN_NB ((N_NODES + SCAN_ITEMS - 1) / SCAN_ITEMS)   // 98

// K1: Wh = h @ W.T, 16 nodes per block; Wh stored as bf16 (gather table for
// k_agg). s1/s2 attention scalars computed from the fp32 accumulator (exact).
__global__ __launch_bounds__(256) void k_wh(const float* __restrict__ h,
                                            const float* __restrict__ W,
                                            const float* __restrict__ a_w,
                                            __hip_bfloat16* __restrict__ Wh16,
                                            float* __restrict__ s1,
                                            float* __restrict__ s2) {
    __shared__ float Ws[OUT_DIM][IN_DIM + 1];   // pad: 2-way bank alias = free
    __shared__ float hs[16][IN_DIM];
    const int tid = threadIdx.x;
    for (int i = tid; i < OUT_DIM * IN_DIM; i += 256)
        Ws[i >> 7][i & 127] = W[i];
    const int node0 = blockIdx.x * 16;
    for (int i = tid; i < 16 * IN_DIM; i += 256) {
        int n = node0 + (i >> 7);
        hs[i >> 7][i & 127] = (n < N_NODES) ? h[(size_t)n * IN_DIM + (i & 127)] : 0.f;
    }
    __syncthreads();
    const int local0 = (tid >> 6) * 4;
    const int d = tid & 63;
    float acc[4] = {0.f, 0.f, 0.f, 0.f};
    for (int k = 0; k < IN_DIM; ++k) {
        float w = Ws[d][k];
        #pragma unroll
        for (int j = 0; j < 4; ++j)
            acc[j] = fmaf(hs[local0 + j][k], w, acc[j]);
    }
    const float aw1 = a_w[d], aw2 = a_w[64 + d];
    #pragma unroll
    for (int j = 0; j < 4; ++j) {
        int n = node0 + local0 + j;
        float v1 = acc[j] * aw1;
        float v2 = acc[j] * aw2;
        #pragma unroll
        for (int off = 32; off > 0; off >>= 1) {
            v1 += __shfl_xor(v1, off, 64);
            v2 += __shfl_xor(v2, off, 64);
        }
        if (n < N_NODES) {
            Wh16[(size_t)n * OUT_DIM + d] = __float2bfloat16(acc[j]);
            if (d == 0) { s1[n] = v1; s2[n] = v2; }
        }
    }
}

// K2: histogram of destination nodes (int atomics into a 400 KB table).
__global__ __launch_bounds__(256) void k_hist(const int* __restrict__ dst,
                                              int* __restrict__ count) {
    int e = blockIdx.x * 256 + threadIdx.x;
    if (e < N_EDGES) atomicAdd(&count[dst[e]], 1);
}

// K3a: per-block partial sums of count.
__global__ __launch_bounds__(256) void k_scan_part(const int* __restrict__ count,
                                                   int* __restrict__ bsum) {
    __shared__ int wsum[4];
    const int tid = threadIdx.x;
    const int base = blockIdx.x * SCAN_ITEMS + tid * 4;
    int s = 0;
    #pragma unroll
    for (int j = 0; j < 4; ++j) {
        int i = base + j;
        if (i < N_NODES) s += count[i];
    }
    #pragma unroll
    for (int off = 32; off > 0; off >>= 1) s += __shfl_xor(s, off, 64);
    if ((tid & 63) == 0) wsum[tid >> 6] = s;
    __syncthreads();
    if (tid == 0) bsum[blockIdx.x] = wsum[0] + wsum[1] + wsum[2] + wsum[3];
}

// K3b: tiny single-block exclusive scan of the block sums.
__global__ __launch_bounds__(128) void k_scan_mid(int* __restrict__ bsum) {
    __shared__ int s[SCAN_NB];
    const int tid = threadIdx.x;
    if (tid < SCAN_NB) s[tid] = bsum[tid];
    __syncthreads();
    if (tid == 0) {
        int run = 0;
        for (int i = 0; i < SCAN_NB; ++i) { int v = s[i]; s[i] = run; run += v; }
    }
    __syncthreads();
    if (tid < SCAN_NB) bsum[tid] = s[tid];
}

// K3c: block-local exclusive scan + block base -> offsets & cursor.
__global__ __launch_bounds__(256) void k_scan_final(const int* __restrict__ count,
                                                    const int* __restrict__ bsum,
                                                    int* __restrict__ offsets,
                                                    int* __restrict__ cursor) {
    __shared__ int wtot[4];
    const int tid = threadIdx.x;
    const int lane = tid & 63;
    const int wid = tid >> 6;
    const int base = blockIdx.x * SCAN_ITEMS + tid * 4;
    int c[4];
    #pragma unroll
    for (int j = 0; j < 4; ++j)
        c[j] = (base + j < N_NODES) ? count[base + j] : 0;
    int tot = c[0] + c[1] + c[2] + c[3];
    int inc = tot;
    #pragma unroll
    for (int off = 1; off < 64; off <<= 1) {
        int u = __shfl_up(inc, off, 64);
        if (lane >= off) inc += u;
    }
    if (lane == 63) wtot[wid] = inc;
    __syncthreads();
    int wbase = 0;
    #pragma unroll
    for (int w = 0; w < 4; ++w) wbase += (w < wid) ? wtot[w] : 0;
    int run = bsum[blockIdx.x] + wbase + (inc - tot);
    #pragma unroll
    for (int j = 0; j < 4; ++j) {
        int i = base + j;
        if (i < N_NODES) { offsets[i] = run; cursor[i] = run; run += c[j]; }
    }
    if (blockIdx.x == 0 && tid == 0) offsets[N_NODES] = N_EDGES;
}

// K4: per-edge: compute ae = exp(leakyrelu(s1[src]+s2[dst])) once, write it
// coalesced in original order, and scatter ONE packed 8B (src, ae) record
// into dst-sorted position.
__global__ __launch_bounds__(256) void k_scatter(const int* __restrict__ ei,
                                                 const float* __restrict__ s1,
                                                 const float* __restrict__ s2,
                                                 int* __restrict__ cursor,
                                                 int2* __restrict__ sa_sorted,
                                                 float* __restrict__ ae_orig) {
    int e = blockIdx.x * 256 + threadIdx.x;
    if (e >= N_EDGES) return;
    int src = ei[e];
    int dst = ei[N_EDGES + e];
    float a = s1[src] + s2[dst];
    a = (a > 0.f) ? a : 0.2f * a;           // leaky_relu(0.2)
    float ae = expf(a);                      // global-max shift cancels exactly
    ae_orig[e] = ae;
    int pos = atomicAdd(&cursor[dst], 1);
    sa_sorted[pos] = make_int2(src, __float_as_int(ae));
}

// K5: one 64-lane wave per dst node; lane == output dim. Cooperative 64-wide
// load of (src, ae) pairs, shuffle-broadcast, bf16 Wh row gather + fma.
// No atomics, no expf, no scattered writes. ELU fused; inv table for k_norm.
__global__ __launch_bounds__(256) void k_agg(const int2* __restrict__ sa_sorted,
                                             const int* __restrict__ offsets,
                                             const __hip_bfloat16* __restrict__ Wh16,
                                             float* __restrict__ out,
                                             float* __restrict__ inv_tab) {
    int gid = blockIdx.x * 256 + threadIdx.x;
    int node = gid >> 6;
    int d = gid & 63;
    if (node >= N_NODES) return;
    const int beg = offsets[node];
    const int end = offsets[node + 1];
    float acc = 0.f, S = 0.f;
    for (int base = beg; base < end; base += 64) {
        const int cnt = min(64, end - base);
        int2 sa = make_int2(0, 0);
        if (base + d < end) sa = sa_sorted[base + d];   // coalesced 512B/wave
        for (int j = 0; j < cnt; ++j) {
            int   srcj = __shfl(sa.x, j, 64);
            float aej  = __int_as_float(__shfl(sa.y, j, 64));
            S += aej;
            float w = __bfloat162float(Wh16[(size_t)srcj * OUT_DIM + d]);
            acc = fmaf(aej, w, acc);                    // 128B coalesced row
        }
    }
    const float inv = 1.f / (S + 1e-9f);
    if (d == 0) inv_tab[node] = inv;
    float o = acc * inv;
    out[(size_t)node * OUT_DIM + d] = (o > 0.f) ? o : expf(o) - 1.f;
}

// K6: alpha_norm in original edge order — fully coalesced reads/writes,
// inv gather hits the 400 KB L2-resident table.
__global__ __launch_bounds__(256) void k_norm(const int* __restrict__ dst_arr,
                                              const float* __restrict__ ae_orig,
                                              const float* __restrict__ inv_tab,
                                              float* __restrict__ alpha_norm) {
    int e = blockIdx.x * 256 + threadIdx.x;
    if (e < N_EDGES) alpha_norm[e] = ae_orig[e] * inv_tab[dst_arr[e]];
}

extern "C" void kernel_launch(void* const* d_in, const int* in_sizes, int n_in,
                              void* d_out, int out_size, void* d_ws, size_t ws_size,
                              hipStream_t stream) {
    const float* h   = (const float*)d_in[0];
    const float* W   = (const float*)d_in[1];
    const float* a_w = (const float*)d_in[2];
    const int*   ei  = (const int*)d_in[3];    // [2, E]: row0=src, row1=dst

    float* out        = (float*)d_out;                       // [N, 64] elu(out)
    float* alpha_norm = out + (size_t)N_NODES * OUT_DIM;     // [E]

    // workspace layout (~34.6 MB); 8B-aligned arrays first
    char* ws = (char*)d_ws;
    int2* sa_sorted = (int2*)ws;            ws += (size_t)N_EDGES * 8;
    float* ae_orig  = (float*)ws;           ws += (size_t)N_EDGES * 4;
    float* s1       = (float*)ws;           ws += (size_t)N_NODES * 4;
    float* s2       = (float*)ws;           ws += (size_t)N_NODES * 4;
    int*   count    = (int*)ws;             ws += (size_t)N_NODES * 4;
    int*   offsets  = (int*)ws;             ws += (size_t)(N_NODES + 1) * 4;
    int*   cursor   = (int*)ws;             ws += (size_t)N_NODES * 4;
    int*   bsum     = (int*)ws;             ws += (size_t)SCAN_NB * 4;
    float* inv_tab  = (float*)ws;           ws += (size_t)N_NODES * 4;
    __hip_bfloat16* Wh16 = (__hip_bfloat16*)ws;  ws += (size_t)N_NODES * OUT_DIM * 2;

    hipMemsetAsync(count, 0, (size_t)N_NODES * 4, stream);

    k_wh<<<(N_NODES + 15) / 16, 256, 0, stream>>>(h, W, a_w, Wh16, s1, s2);
    k_hist<<<(N_EDGES + 255) / 256, 256, 0, stream>>>(ei + N_EDGES, count);
    k_scan_part<<<SCAN_NB, 256, 0, stream>>>(count, bsum);
    k_scan_mid<<<1, 128, 0, stream>>>(bsum);
    k_scan_final<<<SCAN_NB, 256, 0, stream>>>(count, bsum, offsets, cursor);
    k_scatter<<<(N_EDGES + 255) / 256, 256, 0, stream>>>(ei, s1, s2, cursor,
                                                         sa_sorted, ae_orig);
    k_agg<<<(N_NODES * 64 + 255) / 256, 256, 0, stream>>>(sa_sorted, offsets, Wh16,
                                                          out, inv_tab);
    k_norm<<<(N_EDGES + 255) / 256, 256, 0, stream>>>(ei + N_EDGES, ae_orig,
                                                      inv_tab, alpha_norm);
}

// Round 5
// 274.124 us; speedup vs baseline: 2.3914x; 1.2273x over previous
//
#include <hip/hip_runtime.h>
#include <math.h>

#define N_NODES 100000
#define N_EDGES 1600000
#define IN_DIM 128
#define OUT_DIM 64

#define SCAN_ITEMS 1024
#define SCAN_NB ((N_NODES + SCAN_ITEMS - 1) / SCAN_ITEMS)   // 98

typedef short short8 __attribute__((ext_vector_type(8)));   // 8 bf16 in 4 VGPRs
typedef float f32x4 __attribute__((ext_vector_type(4)));

// float -> bf16 bits, round-nearest-even (finite inputs)
__device__ __forceinline__ unsigned short f2bf(float x) {
    unsigned int u = __float_as_uint(x);
    return (unsigned short)((u + 0x7FFFu + ((u >> 16) & 1u)) >> 16);
}
__device__ __forceinline__ float bf2f(unsigned short v) {
    return __uint_as_float(((unsigned int)v) << 16);
}
__device__ __forceinline__ short8 pack_bf16x8(float4 p, float4 q) {
    short8 r;
    r[0] = (short)f2bf(p.x); r[1] = (short)f2bf(p.y);
    r[2] = (short)f2bf(p.z); r[3] = (short)f2bf(p.w);
    r[4] = (short)f2bf(q.x); r[5] = (short)f2bf(q.y);
    r[6] = (short)f2bf(q.z); r[7] = (short)f2bf(q.w);
    return r;
}

// K0: w1[k] = sum_d a_w[d]*W[d][k], w2[k] = sum_d a_w[64+d]*W[d][k].
// (s1 = Wh·a1 = h·(W^T a1) — exact fp32 associativity trick.)
__global__ __launch_bounds__(128) void k_prep(const float* __restrict__ W,
                                              const float* __restrict__ a_w,
                                              float* __restrict__ w1,
                                              float* __restrict__ w2) {
    const int k = threadIdx.x;          // 128 threads, coalesced over k
    float r1 = 0.f, r2 = 0.f;
    #pragma unroll 8
    for (int dd = 0; dd < OUT_DIM; ++dd) {
        float wv = W[dd * IN_DIM + k];
        r1 = fmaf(a_w[dd], wv, r1);
        r2 = fmaf(a_w[OUT_DIM + dd], wv, r2);
    }
    w1[k] = r1; w2[k] = r2;
}

// K1: Wh16 = bf16(h @ W.T) via MFMA 16x16x32_bf16; fp32 s1/s2 fused from the
// fp32 h values (w-trick). Per block: 4 waves x 16 nodes = 64 nodes. No LDS.
// A-layout: lane l holds row (l&15), k = kt*32 + (l>>4)*8 + i.
// B-layout: lane l holds col (l&15), same k pattern; B[k][n] = W[n][k].
// D-layout (verified m89/m91): col = lane&15, row = (lane>>4)*4 + reg.
__global__ __launch_bounds__(256) void k_wh(const float* __restrict__ h,
                                            const float* __restrict__ W,
                                            const float* __restrict__ w1,
                                            const float* __restrict__ w2,
                                            unsigned short* __restrict__ Wh16,
                                            float* __restrict__ s1,
                                            float* __restrict__ s2) {
    const int tid = threadIdx.x;
    const int wv = tid >> 6;
    const int l  = tid & 63;
    const int g  = l >> 4;              // k-group 0..3
    const int lm = l & 15;
    const int node0 = blockIdx.x * 64 + wv * 16;
    const int row = node0 + lm;
    const int rowc = (row < N_NODES) ? row : (N_NODES - 1);
    const float* hrow = h + (size_t)rowc * IN_DIM;

    short8 afrag[4];
    float sp1 = 0.f, sp2 = 0.f;
    #pragma unroll
    for (int kt = 0; kt < 4; ++kt) {
        const int k0 = kt * 32 + g * 8;
        float4 p = *(const float4*)(hrow + k0);
        float4 q = *(const float4*)(hrow + k0 + 4);
        float4 u1 = *(const float4*)(w1 + k0);
        float4 v1 = *(const float4*)(w1 + k0 + 4);
        float4 u2 = *(const float4*)(w2 + k0);
        float4 v2 = *(const float4*)(w2 + k0 + 4);
        sp1 += p.x*u1.x + p.y*u1.y + p.z*u1.z + p.w*u1.w
             + q.x*v1.x + q.y*v1.y + q.z*v1.z + q.w*v1.w;
        sp2 += p.x*u2.x + p.y*u2.y + p.z*u2.z + p.w*u2.w
             + q.x*v2.x + q.y*v2.y + q.z*v2.z + q.w*v2.w;
        afrag[kt] = pack_bf16x8(p, q);
    }
    // lanes {lm, lm+16, lm+32, lm+48} share a row; combine their k-partials
    sp1 += __shfl_xor(sp1, 16, 64); sp1 += __shfl_xor(sp1, 32, 64);
    sp2 += __shfl_xor(sp2, 16, 64); sp2 += __shfl_xor(sp2, 32, 64);
    if (l < 16 && row < N_NODES) { s1[row] = sp1; s2[row] = sp2; }

    f32x4 acc[4] = {f32x4{0,0,0,0}, f32x4{0,0,0,0}, f32x4{0,0,0,0}, f32x4{0,0,0,0}};
    #pragma unroll
    for (int nt = 0; nt < 4; ++nt) {
        #pragma unroll
        for (int kt = 0; kt < 4; ++kt) {
            const float* wr = W + (size_t)(nt * 16 + lm) * IN_DIM + kt * 32 + g * 8;
            float4 p = *(const float4*)wr;
            float4 q = *(const float4*)(wr + 4);
            short8 bfrag = pack_bf16x8(p, q);
            acc[nt] = __builtin_amdgcn_mfma_f32_16x16x32_bf16(afrag[kt], bfrag, acc[nt], 0, 0, 0);
        }
    }
    #pragma unroll
    for (int nt = 0; nt < 4; ++nt) {
        #pragma unroll
        for (int r = 0; r < 4; ++r) {
            int nodo = node0 + g * 4 + r;
            if (nodo < N_NODES)
                Wh16[(size_t)nodo * OUT_DIM + nt * 16 + lm] = f2bf(acc[nt][r]);
        }
    }
}

// K2: histogram of destination nodes.
__global__ __launch_bounds__(256) void k_hist(const int* __restrict__ dst,
                                              int* __restrict__ count) {
    int e = blockIdx.x * 256 + threadIdx.x;
    if (e < N_EDGES) atomicAdd(&count[dst[e]], 1);
}

// K3a/b/c: 3-phase exclusive scan of count -> offsets, cursor.
__global__ __launch_bounds__(256) void k_scan_part(const int* __restrict__ count,
                                                   int* __restrict__ bsum) {
    __shared__ int wsum[4];
    const int tid = threadIdx.x;
    const int base = blockIdx.x * SCAN_ITEMS + tid * 4;
    int s = 0;
    #pragma unroll
    for (int j = 0; j < 4; ++j) {
        int i = base + j;
        if (i < N_NODES) s += count[i];
    }
    #pragma unroll
    for (int off = 32; off > 0; off >>= 1) s += __shfl_xor(s, off, 64);
    if ((tid & 63) == 0) wsum[tid >> 6] = s;
    __syncthreads();
    if (tid == 0) bsum[blockIdx.x] = wsum[0] + wsum[1] + wsum[2] + wsum[3];
}

__global__ __launch_bounds__(128) void k_scan_mid(int* __restrict__ bsum) {
    __shared__ int s[SCAN_NB];
    const int tid = threadIdx.x;
    if (tid < SCAN_NB) s[tid] = bsum[tid];
    __syncthreads();
    if (tid == 0) {
        int run = 0;
        for (int i = 0; i < SCAN_NB; ++i) { int v = s[i]; s[i] = run; run += v; }
    }
    __syncthreads();
    if (tid < SCAN_NB) bsum[tid] = s[tid];
}

__global__ __launch_bounds__(256) void k_scan_final(const int* __restrict__ count,
                                                    const int* __restrict__ bsum,
                                                    int* __restrict__ offsets,
                                                    int* __restrict__ cursor) {
    __shared__ int wtot[4];
    const int tid = threadIdx.x;
    const int lane = tid & 63;
    const int wid = tid >> 6;
    const int base = blockIdx.x * SCAN_ITEMS + tid * 4;
    int c[4];
    #pragma unroll
    for (int j = 0; j < 4; ++j)
        c[j] = (base + j < N_NODES) ? count[base + j] : 0;
    int tot = c[0] + c[1] + c[2] + c[3];
    int inc = tot;
    #pragma unroll
    for (int off = 1; off < 64; off <<= 1) {
        int u = __shfl_up(inc, off, 64);
        if (lane >= off) inc += u;
    }
    if (lane == 63) wtot[wid] = inc;
    __syncthreads();
    int wbase = 0;
    #pragma unroll
    for (int w = 0; w < 4; ++w) wbase += (w < wid) ? wtot[w] : 0;
    int run = bsum[blockIdx.x] + wbase + (inc - tot);
    #pragma unroll
    for (int j = 0; j < 4; ++j) {
        int i = base + j;
        if (i < N_NODES) { offsets[i] = run; cursor[i] = run; run += c[j]; }
    }
    if (blockIdx.x == 0 && tid == 0) offsets[N_NODES] = N_EDGES;
}

// K4: per-edge ae = exp(leakyrelu(s1[src]+s2[dst])); coalesced ae_orig write +
// one packed 8B (src, ae) scatter into dst-sorted position.
__global__ __launch_bounds__(256) void k_scatter(const int* __restrict__ ei,
                                                 const float* __restrict__ s1,
                                                 const float* __restrict__ s2,
                                                 int* __restrict__ cursor,
                                                 int2* __restrict__ sa_sorted,
                                                 float* __restrict__ ae_orig) {
    int e = blockIdx.x * 256 + threadIdx.x;
    if (e >= N_EDGES) return;
    int src = ei[e];
    int dst = ei[N_EDGES + e];
    float a = s1[src] + s2[dst];
    a = (a > 0.f) ? a : 0.2f * a;
    float ae = expf(a);                  // global-max shift cancels exactly
    ae_orig[e] = ae;
    int pos = atomicAdd(&cursor[dst], 1);
    sa_sorted[pos] = make_int2(src, __float_as_int(ae));
}

// K5: one wave per dst node, lane == output dim. Unroll-by-4 with independent
// accumulators: 4 bf16-row gathers in flight (MLP), wave-uniform pair loads.
__global__ __launch_bounds__(256) void k_agg(const int2* __restrict__ sa_sorted,
                                             const int* __restrict__ offsets,
                                             const unsigned short* __restrict__ Wh16,
                                             float* __restrict__ out,
                                             float* __restrict__ inv_tab) {
    int gid = blockIdx.x * 256 + threadIdx.x;
    int node = gid >> 6;
    int d = gid & 63;
    if (node >= N_NODES) return;
    const int beg = offsets[node];
    const int end = offsets[node + 1];
    float acc0 = 0.f, acc1 = 0.f, acc2 = 0.f, acc3 = 0.f, S = 0.f;
    int i = beg;
    for (; i + 4 <= end; i += 4) {
        int2 p0 = sa_sorted[i + 0];
        int2 p1 = sa_sorted[i + 1];
        int2 p2 = sa_sorted[i + 2];
        int2 p3 = sa_sorted[i + 3];
        float g0 = bf2f(Wh16[(size_t)p0.x * OUT_DIM + d]);
        float g1 = bf2f(Wh16[(size_t)p1.x * OUT_DIM + d]);
        float g2 = bf2f(Wh16[(size_t)p2.x * OUT_DIM + d]);
        float g3 = bf2f(Wh16[(size_t)p3.x * OUT_DIM + d]);
        float a0 = __int_as_float(p0.y), a1 = __int_as_float(p1.y);
        float a2 = __int_as_float(p2.y), a3 = __int_as_float(p3.y);
        S += (a0 + a1) + (a2 + a3);
        acc0 = fmaf(a0, g0, acc0);
        acc1 = fmaf(a1, g1, acc1);
        acc2 = fmaf(a2, g2, acc2);
        acc3 = fmaf(a3, g3, acc3);
    }
    for (; i < end; ++i) {
        int2 p = sa_sorted[i];
        float a = __int_as_float(p.y);
        S += a;
        acc0 = fmaf(a, bf2f(Wh16[(size_t)p.x * OUT_DIM + d]), acc0);
    }
    float acc = (acc0 + acc1) + (acc2 + acc3);
    const float inv = 1.f / (S + 1e-9f);
    if (d == 0) inv_tab[node] = inv;
    float o = acc * inv;
    out[(size_t)node * OUT_DIM + d] = (o > 0.f) ? o : expf(o) - 1.f;
}

// K6: alpha_norm in original edge order — fully coalesced.
__global__ __launch_bounds__(256) void k_norm(const int* __restrict__ dst_arr,
                                              const float* __restrict__ ae_orig,
                                              const float* __restrict__ inv_tab,
                                              float* __restrict__ alpha_norm) {
    int e = blockIdx.x * 256 + threadIdx.x;
    if (e < N_EDGES) alpha_norm[e] = ae_orig[e] * inv_tab[dst_arr[e]];
}

extern "C" void kernel_launch(void* const* d_in, const int* in_sizes, int n_in,
                              void* d_out, int out_size, void* d_ws, size_t ws_size,
                              hipStream_t stream) {
    const float* h   = (const float*)d_in[0];
    const float* W   = (const float*)d_in[1];
    const float* a_w = (const float*)d_in[2];
    const int*   ei  = (const int*)d_in[3];    // [2, E]: row0=src, row1=dst

    float* out        = (float*)d_out;                       // [N, 64] elu(out)
    float* alpha_norm = out + (size_t)N_NODES * OUT_DIM;     // [E]

    // workspace layout (~34.6 MB); 8B/16B-aligned arrays first
    char* ws = (char*)d_ws;
    int2* sa_sorted = (int2*)ws;            ws += (size_t)N_EDGES * 8;
    float* ae_orig  = (float*)ws;           ws += (size_t)N_EDGES * 4;
    float* s1       = (float*)ws;           ws += (size_t)N_NODES * 4;
    float* s2       = (float*)ws;           ws += (size_t)N_NODES * 4;
    int*   count    = (int*)ws;             ws += (size_t)N_NODES * 4;
    int*   offsets  = (int*)ws;             ws += (size_t)(N_NODES + 1) * 4;
    int*   cursor   = (int*)ws;             ws += (size_t)N_NODES * 4;
    int*   bsum     = (int*)ws;             ws += (size_t)SCAN_NB * 4;
    float* inv_tab  = (float*)ws;           ws += (size_t)N_NODES * 4;
    float* w1       = (float*)ws;           ws += (size_t)IN_DIM * 4;
    float* w2       = (float*)ws;           ws += (size_t)IN_DIM * 4;
    unsigned short* Wh16 = (unsigned short*)ws;  ws += (size_t)N_NODES * OUT_DIM * 2;

    hipMemsetAsync(count, 0, (size_t)N_NODES * 4, stream);

    k_prep<<<1, 128, 0, stream>>>(W, a_w, w1, w2);
    k_wh<<<(N_NODES + 63) / 64, 256, 0, stream>>>(h, W, w1, w2, Wh16, s1, s2);
    k_hist<<<(N_EDGES + 255) / 256, 256, 0, stream>>>(ei + N_EDGES, count);
    k_scan_part<<<SCAN_NB, 256, 0, stream>>>(count, bsum);
    k_scan_mid<<<1, 128, 0, stream>>>(bsum);
    k_scan_final<<<SCAN_NB, 256, 0, stream>>>(count, bsum, offsets, cursor);
    k_scatter<<<(N_EDGES + 255) / 256, 256, 0, stream>>>(ei, s1, s2, cursor,
                                                         sa_sorted, ae_orig);
    k_agg<<<(N_NODES * 64 + 255) / 256, 256, 0, stream>>>(sa_sorted, offsets, Wh16,
                                                          out, inv_tab);
    k_norm<<<(N_EDGES + 255) / 256, 256, 0, stream>>>(ei + N_EDGES, ae_orig,
                                                      inv_tab, alpha_norm);
}

// Round 6
// 188.811 us; speedup vs baseline: 3.4719x; 1.4518x over previous
//
#include <hip/hip_runtime.h>
#include <math.h>

#define N_NODES 100000
#define N_EDGES 1600000
#define IN_DIM 128
#define OUT_DIM 64

// ---- coarse bucketing geometry ----
#define BSHIFT 9
#define BSIZE  (1 << BSHIFT)                       // 512 dst per bucket
#define NB     ((N_NODES + BSIZE - 1) >> BSHIFT)   // 196 buckets
#define EDGES_PER_BLK 2048
#define NBLK   ((N_EDGES + EDGES_PER_BLK - 1) / EDGES_PER_BLK)   // 782
#define SCANA_LEN (NB * NBLK)                      // 153272
#define SCANA_ITEMS 1024
#define SCANA_NB ((SCANA_LEN + SCANA_ITEMS - 1) / SCANA_ITEMS)   // 150

typedef short short8 __attribute__((ext_vector_type(8)));
typedef float f32x4 __attribute__((ext_vector_type(4)));

__device__ __forceinline__ unsigned short f2bf(float x) {
    unsigned int u = __float_as_uint(x);
    return (unsigned short)((u + 0x7FFFu + ((u >> 16) & 1u)) >> 16);
}
__device__ __forceinline__ float bf2f(unsigned short v) {
    return __uint_as_float(((unsigned int)v) << 16);
}
__device__ __forceinline__ short8 pack_bf16x8(float4 p, float4 q) {
    short8 r;
    r[0] = (short)f2bf(p.x); r[1] = (short)f2bf(p.y);
    r[2] = (short)f2bf(p.z); r[3] = (short)f2bf(p.w);
    r[4] = (short)f2bf(q.x); r[5] = (short)f2bf(q.y);
    r[6] = (short)f2bf(q.z); r[7] = (short)f2bf(q.w);
    return r;
}

// K0: w1 = W^T a1, w2 = W^T a2 (fp32-exact associativity for s1/s2).
__global__ __launch_bounds__(128) void k_prep(const float* __restrict__ W,
                                              const float* __restrict__ a_w,
                                              float* __restrict__ w1,
                                              float* __restrict__ w2) {
    const int k = threadIdx.x;
    float r1 = 0.f, r2 = 0.f;
    #pragma unroll 8
    for (int dd = 0; dd < OUT_DIM; ++dd) {
        float wv = W[dd * IN_DIM + k];
        r1 = fmaf(a_w[dd], wv, r1);
        r2 = fmaf(a_w[OUT_DIM + dd], wv, r2);
    }
    w1[k] = r1; w2[k] = r2;
}

// K1: Wh16 = bf16(h @ W.T) via MFMA 16x16x32_bf16; fp32 s1/s2 fused. No LDS.
__global__ __launch_bounds__(256) void k_wh(const float* __restrict__ h,
                                            const float* __restrict__ W,
                                            const float* __restrict__ w1,
                                            const float* __restrict__ w2,
                                            unsigned short* __restrict__ Wh16,
                                            float* __restrict__ s1,
                                            float* __restrict__ s2) {
    const int tid = threadIdx.x;
    const int wv = tid >> 6;
    const int l  = tid & 63;
    const int g  = l >> 4;
    const int lm = l & 15;
    const int node0 = blockIdx.x * 64 + wv * 16;
    const int row = node0 + lm;
    const int rowc = (row < N_NODES) ? row : (N_NODES - 1);
    const float* hrow = h + (size_t)rowc * IN_DIM;

    short8 afrag[4];
    float sp1 = 0.f, sp2 = 0.f;
    #pragma unroll
    for (int kt = 0; kt < 4; ++kt) {
        const int k0 = kt * 32 + g * 8;
        float4 p = *(const float4*)(hrow + k0);
        float4 q = *(const float4*)(hrow + k0 + 4);
        float4 u1 = *(const float4*)(w1 + k0);
        float4 v1 = *(const float4*)(w1 + k0 + 4);
        float4 u2 = *(const float4*)(w2 + k0);
        float4 v2 = *(const float4*)(w2 + k0 + 4);
        sp1 += p.x*u1.x + p.y*u1.y + p.z*u1.z + p.w*u1.w
             + q.x*v1.x + q.y*v1.y + q.z*v1.z + q.w*v1.w;
        sp2 += p.x*u2.x + p.y*u2.y + p.z*u2.z + p.w*u2.w
             + q.x*v2.x + q.y*v2.y + q.z*v2.z + q.w*v2.w;
        afrag[kt] = pack_bf16x8(p, q);
    }
    sp1 += __shfl_xor(sp1, 16, 64); sp1 += __shfl_xor(sp1, 32, 64);
    sp2 += __shfl_xor(sp2, 16, 64); sp2 += __shfl_xor(sp2, 32, 64);
    if (l < 16 && row < N_NODES) { s1[row] = sp1; s2[row] = sp2; }

    f32x4 acc[4] = {f32x4{0,0,0,0}, f32x4{0,0,0,0}, f32x4{0,0,0,0}, f32x4{0,0,0,0}};
    #pragma unroll
    for (int nt = 0; nt < 4; ++nt) {
        #pragma unroll
        for (int kt = 0; kt < 4; ++kt) {
            const float* wr = W + (size_t)(nt * 16 + lm) * IN_DIM + kt * 32 + g * 8;
            float4 p = *(const float4*)wr;
            float4 q = *(const float4*)(wr + 4);
            short8 bfrag = pack_bf16x8(p, q);
            acc[nt] = __builtin_amdgcn_mfma_f32_16x16x32_bf16(afrag[kt], bfrag, acc[nt], 0, 0, 0);
        }
    }
    #pragma unroll
    for (int nt = 0; nt < 4; ++nt) {
        #pragma unroll
        for (int r = 0; r < 4; ++r) {
            int nodo = node0 + g * 4 + r;
            if (nodo < N_NODES)
                Wh16[(size_t)nodo * OUT_DIM + nt * 16 + lm] = f2bf(acc[nt][r]);
        }
    }
}

// K2: per-(block,bucket) histogram -> hist_t[bucket*NBLK + blk].
__global__ __launch_bounds__(256) void k_histA(const int* __restrict__ dst,
                                               int* __restrict__ hist_t) {
    __shared__ int lhist[NB];
    const int tid = threadIdx.x;
    const int blk = blockIdx.x;
    if (tid < NB) lhist[tid] = 0;
    __syncthreads();
    const int e0 = blk * EDGES_PER_BLK;
    #pragma unroll
    for (int j = 0; j < 8; ++j) {
        int e = e0 + j * 256 + tid;
        if (e < N_EDGES) atomicAdd(&lhist[dst[e] >> BSHIFT], 1);
    }
    __syncthreads();
    if (tid < NB) hist_t[tid * NBLK + blk] = lhist[tid];
}

// K3a/b/c: 3-phase exclusive scan of hist_t (len 153272) -> flat_scan.
__global__ __launch_bounds__(256) void k_scanA_part(const int* __restrict__ in,
                                                    int* __restrict__ bsum) {
    __shared__ int wsum[4];
    const int tid = threadIdx.x;
    const int base = blockIdx.x * SCANA_ITEMS + tid * 4;
    int s = 0;
    #pragma unroll
    for (int j = 0; j < 4; ++j) {
        int i = base + j;
        if (i < SCANA_LEN) s += in[i];
    }
    #pragma unroll
    for (int off = 32; off > 0; off >>= 1) s += __shfl_xor(s, off, 64);
    if ((tid & 63) == 0) wsum[tid >> 6] = s;
    __syncthreads();
    if (tid == 0) bsum[blockIdx.x] = wsum[0] + wsum[1] + wsum[2] + wsum[3];
}

__global__ __launch_bounds__(256) void k_scanA_mid(int* __restrict__ bsum) {
    __shared__ int s[SCANA_NB];
    const int tid = threadIdx.x;
    if (tid < SCANA_NB) s[tid] = bsum[tid];
    __syncthreads();
    if (tid == 0) {
        int run = 0;
        for (int i = 0; i < SCANA_NB; ++i) { int v = s[i]; s[i] = run; run += v; }
    }
    __syncthreads();
    if (tid < SCANA_NB) bsum[tid] = s[tid];
}

__global__ __launch_bounds__(256) void k_scanA_final(const int* __restrict__ in,
                                                     const int* __restrict__ bsum,
                                                     int* __restrict__ outscan) {
    __shared__ int wtot[4];
    const int tid = threadIdx.x;
    const int lane = tid & 63;
    const int wid = tid >> 6;
    const int base = blockIdx.x * SCANA_ITEMS + tid * 4;
    int c[4];
    #pragma unroll
    for (int j = 0; j < 4; ++j)
        c[j] = (base + j < SCANA_LEN) ? in[base + j] : 0;
    int tot = c[0] + c[1] + c[2] + c[3];
    int inc = tot;
    #pragma unroll
    for (int off = 1; off < 64; off <<= 1) {
        int u = __shfl_up(inc, off, 64);
        if (lane >= off) inc += u;
    }
    if (lane == 63) wtot[wid] = inc;
    __syncthreads();
    int wbase = 0;
    #pragma unroll
    for (int w = 0; w < 4; ++w) wbase += (w < wid) ? wtot[w] : 0;
    int run = bsum[blockIdx.x] + wbase + (inc - tot);
    #pragma unroll
    for (int j = 0; j < 4; ++j) {
        int i = base + j;
        if (i < SCANA_LEN) { outscan[i] = run; run += c[j]; }
    }
}

// K4: per-edge ae + coarse binning. Each block owns private contiguous output
// ranges per bucket (from flat_scan) -> LDS cursors, no global atomics.
// Record: word0 = src | (dstlocal << 17)  (src < 2^17, dstlocal < 512), word1 = ae.
__global__ __launch_bounds__(256) void k_binA(const int* __restrict__ ei,
                                              const float* __restrict__ s1,
                                              const float* __restrict__ s2,
                                              const int* __restrict__ flat_scan,
                                              int2* __restrict__ brec,
                                              float* __restrict__ ae_orig) {
    __shared__ int lbase[NB];
    __shared__ int lcur[NB];
    const int tid = threadIdx.x;
    const int blk = blockIdx.x;
    if (tid < NB) { lbase[tid] = flat_scan[tid * NBLK + blk]; lcur[tid] = 0; }
    __syncthreads();
    const int e0 = blk * EDGES_PER_BLK;
    #pragma unroll
    for (int j = 0; j < 8; ++j) {
        int e = e0 + j * 256 + tid;
        if (e >= N_EDGES) continue;
        int src = ei[e];
        int dst = ei[N_EDGES + e];
        float a = s1[src] + s2[dst];
        a = (a > 0.f) ? a : 0.2f * a;            // leaky_relu(0.2)
        float ae = expf(a);                       // global-max shift cancels
        ae_orig[e] = ae;
        int b = dst >> BSHIFT;
        int r = atomicAdd(&lcur[b], 1);           // LDS atomic
        brec[lbase[b] + r] = make_int2(src | ((dst & (BSIZE - 1)) << 17),
                                       __float_as_int(ae));
    }
}

// K5: fine sort within each bucket. One block per bucket: LDS per-dst
// histogram + scan -> offsets[] (replaces global hist/scan) + exact-position
// (src, ae) records in a block-exclusive ~64KB range.
__global__ __launch_bounds__(256) void k_fine(const int2* __restrict__ brec,
                                              const int* __restrict__ flat_scan,
                                              int* __restrict__ offsets,
                                              int2* __restrict__ sa_sorted) {
    __shared__ int lhist[BSIZE];
    __shared__ int lofs[BSIZE];
    __shared__ int lcur[BSIZE];
    __shared__ int wsum[4];
    const int tid = threadIdx.x;
    const int lane = tid & 63;
    const int wid = tid >> 6;
    const int b = blockIdx.x;
    const int base = flat_scan[b * NBLK];
    const int endp = (b + 1 < NB) ? flat_scan[(b + 1) * NBLK] : N_EDGES;
    const int cnt = endp - base;
    lhist[tid] = 0; lhist[tid + 256] = 0;
    __syncthreads();
    for (int i = tid; i < cnt; i += 256)
        atomicAdd(&lhist[(unsigned)brec[base + i].x >> 17], 1);
    __syncthreads();
    // exclusive scan over 512 bins (2 bins/thread)
    int c0 = lhist[2 * tid], c1 = lhist[2 * tid + 1];
    int s = c0 + c1;
    int inc = s;
    #pragma unroll
    for (int off = 1; off < 64; off <<= 1) {
        int u = __shfl_up(inc, off, 64);
        if (lane >= off) inc += u;
    }
    if (lane == 63) wsum[wid] = inc;
    __syncthreads();
    int wb = 0;
    #pragma unroll
    for (int w = 0; w < 4; ++w) wb += (w < wid) ? wsum[w] : 0;
    int ex = wb + inc - s;
    lofs[2 * tid] = ex; lofs[2 * tid + 1] = ex + c0;
    lcur[2 * tid] = ex; lcur[2 * tid + 1] = ex + c0;
    __syncthreads();
    // per-dst global offsets (coalesced)
    const int dst0 = b << BSHIFT;
    #pragma unroll
    for (int j = 0; j < 2; ++j) {
        int jj = tid + j * 256;
        int node = dst0 + jj;
        if (node < N_NODES) offsets[node] = base + lofs[jj];
    }
    if (b == NB - 1 && tid == 0) offsets[N_NODES] = N_EDGES;
    // scatter to exact sorted position (block-exclusive region)
    for (int i = tid; i < cnt; i += 256) {
        int2 rec = brec[base + i];
        int dstl = (unsigned)rec.x >> 17;
        int pos = base + atomicAdd(&lcur[dstl], 1);
        sa_sorted[pos] = make_int2(rec.x & 0x1FFFF, rec.y);
    }
}

// K6: one wave per dst node, lane == output dim. Unroll-by-4 independent
// accumulators, wave-uniform pair loads, bf16 row gathers.
__global__ __launch_bounds__(256) void k_agg(const int2* __restrict__ sa_sorted,
                                             const int* __restrict__ offsets,
                                             const unsigned short* __restrict__ Wh16,
                                             float* __restrict__ out,
                                             float* __restrict__ inv_tab) {
    int gid = blockIdx.x * 256 + threadIdx.x;
    int node = gid >> 6;
    int d = gid & 63;
    if (node >= N_NODES) return;
    const int beg = offsets[node];
    const int end = offsets[node + 1];
    float acc0 = 0.f, acc1 = 0.f, acc2 = 0.f, acc3 = 0.f, S = 0.f;
    int i = beg;
    for (; i + 4 <= end; i += 4) {
        int2 p0 = sa_sorted[i + 0];
        int2 p1 = sa_sorted[i + 1];
        int2 p2 = sa_sorted[i + 2];
        int2 p3 = sa_sorted[i + 3];
        float g0 = bf2f(Wh16[(size_t)p0.x * OUT_DIM + d]);
        float g1 = bf2f(Wh16[(size_t)p1.x * OUT_DIM + d]);
        float g2 = bf2f(Wh16[(size_t)p2.x * OUT_DIM + d]);
        float g3 = bf2f(Wh16[(size_t)p3.x * OUT_DIM + d]);
        float a0 = __int_as_float(p0.y), a1 = __int_as_float(p1.y);
        float a2 = __int_as_float(p2.y), a3 = __int_as_float(p3.y);
        S += (a0 + a1) + (a2 + a3);
        acc0 = fmaf(a0, g0, acc0);
        acc1 = fmaf(a1, g1, acc1);
        acc2 = fmaf(a2, g2, acc2);
        acc3 = fmaf(a3, g3, acc3);
    }
    for (; i < end; ++i) {
        int2 p = sa_sorted[i];
        float a = __int_as_float(p.y);
        S += a;
        acc0 = fmaf(a, bf2f(Wh16[(size_t)p.x * OUT_DIM + d]), acc0);
    }
    float acc = (acc0 + acc1) + (acc2 + acc3);
    const float inv = 1.f / (S + 1e-9f);
    if (d == 0) inv_tab[node] = inv;
    float o = acc * inv;
    out[(size_t)node * OUT_DIM + d] = (o > 0.f) ? o : expf(o) - 1.f;
}

// K7: alpha_norm in original edge order — fully coalesced.
__global__ __launch_bounds__(256) void k_norm(const int* __restrict__ dst_arr,
                                              const float* __restrict__ ae_orig,
                                              const float* __restrict__ inv_tab,
                                              float* __restrict__ alpha_norm) {
    int e = blockIdx.x * 256 + threadIdx.x;
    if (e < N_EDGES) alpha_norm[e] = ae_orig[e] * inv_tab[dst_arr[e]];
}

extern "C" void kernel_launch(void* const* d_in, const int* in_sizes, int n_in,
                              void* d_out, int out_size, void* d_ws, size_t ws_size,
                              hipStream_t stream) {
    const float* h   = (const float*)d_in[0];
    const float* W   = (const float*)d_in[1];
    const float* a_w = (const float*)d_in[2];
    const int*   ei  = (const int*)d_in[3];    // [2, E]: row0=src, row1=dst

    float* out        = (float*)d_out;                       // [N, 64] elu(out)
    float* alpha_norm = out + (size_t)N_NODES * OUT_DIM;     // [E]

    // workspace layout (~48 MB); 8B/16B-aligned arrays first
    char* ws = (char*)d_ws;
    int2* brec      = (int2*)ws;            ws += (size_t)N_EDGES * 8;
    int2* sa_sorted = (int2*)ws;            ws += (size_t)N_EDGES * 8;
    float* ae_orig  = (float*)ws;           ws += (size_t)N_EDGES * 4;
    float* s1       = (float*)ws;           ws += (size_t)N_NODES * 4;
    float* s2       = (float*)ws;           ws += (size_t)N_NODES * 4;
    int*   hist_t   = (int*)ws;             ws += (size_t)SCANA_LEN * 4;
    int*   flat_scan= (int*)ws;             ws += (size_t)SCANA_LEN * 4;
    int*   bsum     = (int*)ws;             ws += (size_t)SCANA_NB * 4;
    int*   offsets  = (int*)ws;             ws += (size_t)(N_NODES + 1) * 4;
    float* inv_tab  = (float*)ws;           ws += (size_t)N_NODES * 4;
    float* w1       = (float*)ws;           ws += (size_t)IN_DIM * 4;
    float* w2       = (float*)ws;           ws += (size_t)IN_DIM * 4;
    unsigned short* Wh16 = (unsigned short*)ws;  ws += (size_t)N_NODES * OUT_DIM * 2;

    k_prep<<<1, 128, 0, stream>>>(W, a_w, w1, w2);
    k_wh<<<(N_NODES + 63) / 64, 256, 0, stream>>>(h, W, w1, w2, Wh16, s1, s2);
    k_histA<<<NBLK, 256, 0, stream>>>(ei + N_EDGES, hist_t);
    k_scanA_part<<<SCANA_NB, 256, 0, stream>>>(hist_t, bsum);
    k_scanA_mid<<<1, 256, 0, stream>>>(bsum);
    k_scanA_final<<<SCANA_NB, 256, 0, stream>>>(hist_t, bsum, flat_scan);
    k_binA<<<NBLK, 256, 0, stream>>>(ei, s1, s2, flat_scan, brec, ae_orig);
    k_fine<<<NB, 256, 0, stream>>>(brec, flat_scan, offsets, sa_sorted);
    k_agg<<<(N_NODES * 64 + 255) / 256, 256, 0, stream>>>(sa_sorted, offsets, Wh16,
                                                          out, inv_tab);
    k_norm<<<(N_EDGES + 255) / 256, 256, 0, stream>>>(ei + N_EDGES, ae_orig,
                                                      inv_tab, alpha_norm);
}

// Round 7
// 164.606 us; speedup vs baseline: 3.9824x; 1.1470x over previous
//
#include <hip/hip_runtime.h>
#include <math.h>

#define N_NODES 100000
#define N_EDGES 1600000
#define IN_DIM 128
#define OUT_DIM 64

// ---- coarse bucketing geometry ----
#define BSHIFT 9
#define BSIZE  (1 << BSHIFT)                       // 512 dst per bucket
#define NB     ((N_NODES + BSIZE - 1) >> BSHIFT)   // 196 buckets
#define EDGES_PER_BLK 2048
#define NBLK   ((N_EDGES + EDGES_PER_BLK - 1) / EDGES_PER_BLK)   // 782
#define SCANA_LEN (NB * NBLK)                      // 153272
#define SCANA_ITEMS 1024
#define SCANA_NB ((SCANA_LEN + SCANA_ITEMS - 1) / SCANA_ITEMS)   // 150

typedef short short8 __attribute__((ext_vector_type(8)));
typedef float f32x4 __attribute__((ext_vector_type(4)));

__device__ __forceinline__ unsigned short f2bf(float x) {
    unsigned int u = __float_as_uint(x);
    return (unsigned short)((u + 0x7FFFu + ((u >> 16) & 1u)) >> 16);
}
__device__ __forceinline__ short8 pack_bf16x8(float4 p, float4 q) {
    short8 r;
    r[0] = (short)f2bf(p.x); r[1] = (short)f2bf(p.y);
    r[2] = (short)f2bf(p.z); r[3] = (short)f2bf(p.w);
    r[4] = (short)f2bf(q.x); r[5] = (short)f2bf(q.y);
    r[6] = (short)f2bf(q.z); r[7] = (short)f2bf(q.w);
    return r;
}

// K1: per-(block,bucket) histogram. Block 0 additionally computes
// w1 = W^T a1, w2 = W^T a2 (fp32-exact associativity trick for s1/s2).
__global__ __launch_bounds__(256) void k_histA(const int* __restrict__ dst,
                                               int* __restrict__ hist_t,
                                               const float* __restrict__ W,
                                               const float* __restrict__ a_w,
                                               float* __restrict__ w1,
                                               float* __restrict__ w2) {
    __shared__ int lhist[NB];
    const int tid = threadIdx.x;
    const int blk = blockIdx.x;
    if (blk == 0 && tid < IN_DIM) {
        float r1 = 0.f, r2 = 0.f;
        #pragma unroll 8
        for (int dd = 0; dd < OUT_DIM; ++dd) {
            float wv = W[dd * IN_DIM + tid];
            r1 = fmaf(a_w[dd], wv, r1);
            r2 = fmaf(a_w[OUT_DIM + dd], wv, r2);
        }
        w1[tid] = r1; w2[tid] = r2;
    }
    if (tid < NB) lhist[tid] = 0;
    __syncthreads();
    const int e0 = blk * EDGES_PER_BLK;
    #pragma unroll
    for (int j = 0; j < 8; ++j) {
        int e = e0 + j * 256 + tid;
        if (e < N_EDGES) atomicAdd(&lhist[dst[e] >> BSHIFT], 1);
    }
    __syncthreads();
    if (tid < NB) hist_t[tid * NBLK + blk] = lhist[tid];
}

// K2: Wh16 = bf16(h @ W.T) via MFMA 16x16x32_bf16; fp32 s1/s2 fused. No LDS.
__global__ __launch_bounds__(256) void k_wh(const float* __restrict__ h,
                                            const float* __restrict__ W,
                                            const float* __restrict__ w1,
                                            const float* __restrict__ w2,
                                            unsigned short* __restrict__ Wh16,
                                            float* __restrict__ s1,
                                            float* __restrict__ s2) {
    const int tid = threadIdx.x;
    const int wv = tid >> 6;
    const int l  = tid & 63;
    const int g  = l >> 4;
    const int lm = l & 15;
    const int node0 = blockIdx.x * 64 + wv * 16;
    const int row = node0 + lm;
    const int rowc = (row < N_NODES) ? row : (N_NODES - 1);
    const float* hrow = h + (size_t)rowc * IN_DIM;

    short8 afrag[4];
    float sp1 = 0.f, sp2 = 0.f;
    #pragma unroll
    for (int kt = 0; kt < 4; ++kt) {
        const int k0 = kt * 32 + g * 8;
        float4 p = *(const float4*)(hrow + k0);
        float4 q = *(const float4*)(hrow + k0 + 4);
        float4 u1 = *(const float4*)(w1 + k0);
        float4 v1 = *(const float4*)(w1 + k0 + 4);
        float4 u2 = *(const float4*)(w2 + k0);
        float4 v2 = *(const float4*)(w2 + k0 + 4);
        sp1 += p.x*u1.x + p.y*u1.y + p.z*u1.z + p.w*u1.w
             + q.x*v1.x + q.y*v1.y + q.z*v1.z + q.w*v1.w;
        sp2 += p.x*u2.x + p.y*u2.y + p.z*u2.z + p.w*u2.w
             + q.x*v2.x + q.y*v2.y + q.z*v2.z + q.w*v2.w;
        afrag[kt] = pack_bf16x8(p, q);
    }
    sp1 += __shfl_xor(sp1, 16, 64); sp1 += __shfl_xor(sp1, 32, 64);
    sp2 += __shfl_xor(sp2, 16, 64); sp2 += __shfl_xor(sp2, 32, 64);
    if (l < 16 && row < N_NODES) { s1[row] = sp1; s2[row] = sp2; }

    f32x4 acc[4] = {f32x4{0,0,0,0}, f32x4{0,0,0,0}, f32x4{0,0,0,0}, f32x4{0,0,0,0}};
    #pragma unroll
    for (int nt = 0; nt < 4; ++nt) {
        #pragma unroll
        for (int kt = 0; kt < 4; ++kt) {
            const float* wr = W + (size_t)(nt * 16 + lm) * IN_DIM + kt * 32 + g * 8;
            float4 p = *(const float4*)wr;
            float4 q = *(const float4*)(wr + 4);
            short8 bfrag = pack_bf16x8(p, q);
            acc[nt] = __builtin_amdgcn_mfma_f32_16x16x32_bf16(afrag[kt], bfrag, acc[nt], 0, 0, 0);
        }
    }
    #pragma unroll
    for (int nt = 0; nt < 4; ++nt) {
        #pragma unroll
        for (int r = 0; r < 4; ++r) {
            int nodo = node0 + g * 4 + r;
            if (nodo < N_NODES)
                Wh16[(size_t)nodo * OUT_DIM + nt * 16 + lm] = f2bf(acc[nt][r]);
        }
    }
}

// K3a/b/c: 3-phase exclusive scan of hist_t -> flat_scan.
__global__ __launch_bounds__(256) void k_scanA_part(const int* __restrict__ in,
                                                    int* __restrict__ bsum) {
    __shared__ int wsum[4];
    const int tid = threadIdx.x;
    const int base = blockIdx.x * SCANA_ITEMS + tid * 4;
    int s = 0;
    #pragma unroll
    for (int j = 0; j < 4; ++j) {
        int i = base + j;
        if (i < SCANA_LEN) s += in[i];
    }
    #pragma unroll
    for (int off = 32; off > 0; off >>= 1) s += __shfl_xor(s, off, 64);
    if ((tid & 63) == 0) wsum[tid >> 6] = s;
    __syncthreads();
    if (tid == 0) bsum[blockIdx.x] = wsum[0] + wsum[1] + wsum[2] + wsum[3];
}

// Parallel Hillis-Steele exclusive scan of the SCANA_NB (=150) block sums.
__global__ __launch_bounds__(256) void k_scanA_mid(int* __restrict__ bsum) {
    __shared__ int s[256];
    const int tid = threadIdx.x;
    s[tid] = (tid < SCANA_NB) ? bsum[tid] : 0;
    __syncthreads();
    #pragma unroll
    for (int off = 1; off < 256; off <<= 1) {
        int u = (tid >= off) ? s[tid - off] : 0;
        __syncthreads();
        s[tid] += u;
        __syncthreads();
    }
    if (tid < SCANA_NB) bsum[tid] = (tid > 0) ? s[tid - 1] : 0;
}

__global__ __launch_bounds__(256) void k_scanA_final(const int* __restrict__ in,
                                                     const int* __restrict__ bsum,
                                                     int* __restrict__ outscan) {
    __shared__ int wtot[4];
    const int tid = threadIdx.x;
    const int lane = tid & 63;
    const int wid = tid >> 6;
    const int base = blockIdx.x * SCANA_ITEMS + tid * 4;
    int c[4];
    #pragma unroll
    for (int j = 0; j < 4; ++j)
        c[j] = (base + j < SCANA_LEN) ? in[base + j] : 0;
    int tot = c[0] + c[1] + c[2] + c[3];
    int inc = tot;
    #pragma unroll
    for (int off = 1; off < 64; off <<= 1) {
        int u = __shfl_up(inc, off, 64);
        if (lane >= off) inc += u;
    }
    if (lane == 63) wtot[wid] = inc;
    __syncthreads();
    int wbase = 0;
    #pragma unroll
    for (int w = 0; w < 4; ++w) wbase += (w < wid) ? wtot[w] : 0;
    int run = bsum[blockIdx.x] + wbase + (inc - tot);
    #pragma unroll
    for (int j = 0; j < 4; ++j) {
        int i = base + j;
        if (i < SCANA_LEN) { outscan[i] = run; run += c[j]; }
    }
}

// K4: per-edge ae + coarse binning into block-private bucket ranges.
// Record: word0 = src | (dstlocal << 17), word1 = ae bits.
__global__ __launch_bounds__(256) void k_binA(const int* __restrict__ ei,
                                              const float* __restrict__ s1,
                                              const float* __restrict__ s2,
                                              const int* __restrict__ flat_scan,
                                              int2* __restrict__ brec,
                                              float* __restrict__ ae_orig) {
    __shared__ int lbase[NB];
    __shared__ int lcur[NB];
    const int tid = threadIdx.x;
    const int blk = blockIdx.x;
    if (tid < NB) { lbase[tid] = flat_scan[tid * NBLK + blk]; lcur[tid] = 0; }
    __syncthreads();
    const int e0 = blk * EDGES_PER_BLK;
    #pragma unroll
    for (int j = 0; j < 8; ++j) {
        int e = e0 + j * 256 + tid;
        if (e >= N_EDGES) continue;
        int src = ei[e];
        int dst = ei[N_EDGES + e];
        float a = s1[src] + s2[dst];
        a = (a > 0.f) ? a : 0.2f * a;            // leaky_relu(0.2)
        float ae = expf(a);                       // global-max shift cancels
        ae_orig[e] = ae;
        int b = dst >> BSHIFT;
        int r = atomicAdd(&lcur[b], 1);           // LDS atomic
        brec[lbase[b] + r] = make_int2(src | ((dst & (BSIZE - 1)) << 17),
                                       __float_as_int(ae));
    }
}

// K5: fine sort within each bucket -> offsets[] + dst-sorted (src, ae).
__global__ __launch_bounds__(256) void k_fine(const int2* __restrict__ brec,
                                              const int* __restrict__ flat_scan,
                                              int* __restrict__ offsets,
                                              int2* __restrict__ sa_sorted) {
    __shared__ int lhist[BSIZE];
    __shared__ int lofs[BSIZE];
    __shared__ int lcur[BSIZE];
    __shared__ int wsum[4];
    const int tid = threadIdx.x;
    const int lane = tid & 63;
    const int wid = tid >> 6;
    const int b = blockIdx.x;
    const int base = flat_scan[b * NBLK];
    const int endp = (b + 1 < NB) ? flat_scan[(b + 1) * NBLK] : N_EDGES;
    const int cnt = endp - base;
    lhist[tid] = 0; lhist[tid + 256] = 0;
    __syncthreads();
    for (int i = tid; i < cnt; i += 256)
        atomicAdd(&lhist[(unsigned)brec[base + i].x >> 17], 1);
    __syncthreads();
    int c0 = lhist[2 * tid], c1 = lhist[2 * tid + 1];
    int s = c0 + c1;
    int inc = s;
    #pragma unroll
    for (int off = 1; off < 64; off <<= 1) {
        int u = __shfl_up(inc, off, 64);
        if (lane >= off) inc += u;
    }
    if (lane == 63) wsum[wid] = inc;
    __syncthreads();
    int wb = 0;
    #pragma unroll
    for (int w = 0; w < 4; ++w) wb += (w < wid) ? wsum[w] : 0;
    int ex = wb + inc - s;
    lofs[2 * tid] = ex; lofs[2 * tid + 1] = ex + c0;
    lcur[2 * tid] = ex; lcur[2 * tid + 1] = ex + c0;
    __syncthreads();
    const int dst0 = b << BSHIFT;
    #pragma unroll
    for (int j = 0; j < 2; ++j) {
        int jj = tid + j * 256;
        int node = dst0 + jj;
        if (node < N_NODES) offsets[node] = base + lofs[jj];
    }
    if (b == NB - 1 && tid == 0) offsets[N_NODES] = N_EDGES;
    for (int i = tid; i < cnt; i += 256) {
        int2 rec = brec[base + i];
        int dstl = (unsigned)rec.x >> 17;
        int pos = base + atomicAdd(&lcur[dstl], 1);
        sa_sorted[pos] = make_int2(rec.x & 0x1FFFF, rec.y);
    }
}

// K6: one wave per dst node. 8 lanes per edge (lane = slot g=l>>3, octet
// o=l&7): per-lane int2 pair load + one dwordx4 (8 bf16 dims) row load;
// 16 edges in flight; final shfl_xor(8,16,32) folds slots. ELU fused.
__global__ __launch_bounds__(256) void k_agg(const int2* __restrict__ sa_sorted,
                                             const int* __restrict__ offsets,
                                             const unsigned short* __restrict__ Wh16,
                                             float* __restrict__ out,
                                             float* __restrict__ inv_tab) {
    const int gid = blockIdx.x * 256 + threadIdx.x;
    const int node = gid >> 6;
    const int l = gid & 63;
    if (node >= N_NODES) return;
    const int g = l >> 3;       // edge slot 0..7
    const int o = l & 7;        // dim octet 0..7 (dims o*8 .. o*8+7)
    const int beg = offsets[node];
    const int end = offsets[node + 1];
    float acc[8] = {0.f, 0.f, 0.f, 0.f, 0.f, 0.f, 0.f, 0.f};
    float S = 0.f;
    int i = beg;
    for (; i + 16 <= end; i += 16) {
        int2 pA = sa_sorted[i + g];
        int2 pB = sa_sorted[i + 8 + g];
        const int4 rA = *(const int4*)(Wh16 + ((size_t)pA.x << 6) + (o << 3));
        const int4 rB = *(const int4*)(Wh16 + ((size_t)pB.x << 6) + (o << 3));
        float aeA = __int_as_float(pA.y);
        float aeB = __int_as_float(pB.y);
        S += aeA + aeB;
        #pragma unroll
        for (int j = 0; j < 4; ++j) {
            int vA = ((const int*)&rA)[j];
            acc[2*j]   = fmaf(aeA, __uint_as_float((unsigned)vA << 16), acc[2*j]);
            acc[2*j+1] = fmaf(aeA, __uint_as_float((unsigned)vA & 0xFFFF0000u), acc[2*j+1]);
        }
        #pragma unroll
        for (int j = 0; j < 4; ++j) {
            int vB = ((const int*)&rB)[j];
            acc[2*j]   = fmaf(aeB, __uint_as_float((unsigned)vB << 16), acc[2*j]);
            acc[2*j+1] = fmaf(aeB, __uint_as_float((unsigned)vB & 0xFFFF0000u), acc[2*j+1]);
        }
    }
    for (; i < end; i += 8) {
        int idx = i + g;
        int2 p = (idx < end) ? sa_sorted[idx] : make_int2(0, 0);
        const int4 r = *(const int4*)(Wh16 + ((size_t)p.x << 6) + (o << 3));
        float ae = __int_as_float(p.y);          // 0 for masked lanes
        S += ae;
        #pragma unroll
        for (int j = 0; j < 4; ++j) {
            int v = ((const int*)&r)[j];
            acc[2*j]   = fmaf(ae, __uint_as_float((unsigned)v << 16), acc[2*j]);
            acc[2*j+1] = fmaf(ae, __uint_as_float((unsigned)v & 0xFFFF0000u), acc[2*j+1]);
        }
    }
    // fold the 8 edge slots (xor over lane bits 3,4,5)
    #pragma unroll
    for (int m = 8; m <= 32; m <<= 1) {
        S += __shfl_xor(S, m, 64);
        #pragma unroll
        for (int j = 0; j < 8; ++j) acc[j] += __shfl_xor(acc[j], m, 64);
    }
    const float inv = 1.f / (S + 1e-9f);
    if (l == 0) inv_tab[node] = inv;
    if (g == 0) {                               // lanes 0..7 write 32B each
        float e[8];
        #pragma unroll
        for (int j = 0; j < 8; ++j) {
            float x = acc[j] * inv;
            e[j] = (x > 0.f) ? x : expf(x) - 1.f;
        }
        float* orow = out + (size_t)node * OUT_DIM + o * 8;
        *(float4*)orow = make_float4(e[0], e[1], e[2], e[3]);
        *(float4*)(orow + 4) = make_float4(e[4], e[5], e[6], e[7]);
    }
}

// K7: alpha_norm in original edge order, x4 vectorized.
__global__ __launch_bounds__(256) void k_norm(const int* __restrict__ dst_arr,
                                              const float* __restrict__ ae_orig,
                                              const float* __restrict__ inv_tab,
                                              float* __restrict__ alpha_norm) {
    int t = blockIdx.x * 256 + threadIdx.x;
    if (t >= N_EDGES / 4) return;
    int4 d4 = ((const int4*)dst_arr)[t];
    float4 a4 = ((const float4*)ae_orig)[t];
    float4 r;
    r.x = a4.x * inv_tab[d4.x];
    r.y = a4.y * inv_tab[d4.y];
    r.z = a4.z * inv_tab[d4.z];
    r.w = a4.w * inv_tab[d4.w];
    ((float4*)alpha_norm)[t] = r;
}

extern "C" void kernel_launch(void* const* d_in, const int* in_sizes, int n_in,
                              void* d_out, int out_size, void* d_ws, size_t ws_size,
                              hipStream_t stream) {
    const float* h   = (const float*)d_in[0];
    const float* W   = (const float*)d_in[1];
    const float* a_w = (const float*)d_in[2];
    const int*   ei  = (const int*)d_in[3];    // [2, E]: row0=src, row1=dst

    float* out        = (float*)d_out;                       // [N, 64] elu(out)
    float* alpha_norm = out + (size_t)N_NODES * OUT_DIM;     // [E]

    // workspace layout (~46 MB); 16B-aligned arrays first
    char* ws = (char*)d_ws;
    int2* brec      = (int2*)ws;            ws += (size_t)N_EDGES * 8;
    int2* sa_sorted = (int2*)ws;            ws += (size_t)N_EDGES * 8;
    unsigned short* Wh16 = (unsigned short*)ws;  ws += (size_t)N_NODES * OUT_DIM * 2;
    float* ae_orig  = (float*)ws;           ws += (size_t)N_EDGES * 4;
    float* s1       = (float*)ws;           ws += (size_t)N_NODES * 4;
    float* s2       = (float*)ws;           ws += (size_t)N_NODES * 4;
    int*   hist_t   = (int*)ws;             ws += (size_t)SCANA_LEN * 4;
    int*   flat_scan= (int*)ws;             ws += (size_t)SCANA_LEN * 4;
    int*   bsum     = (int*)ws;             ws += (size_t)SCANA_NB * 4;
    int*   offsets  = (int*)ws;             ws += (size_t)(N_NODES + 1) * 4;
    float* inv_tab  = (float*)ws;           ws += (size_t)N_NODES * 4;
    float* w1       = (float*)ws;           ws += (size_t)IN_DIM * 4;
    float* w2       = (float*)ws;           ws += (size_t)IN_DIM * 4;

    k_histA<<<NBLK, 256, 0, stream>>>(ei + N_EDGES, hist_t, W, a_w, w1, w2);
    k_wh<<<(N_NODES + 63) / 64, 256, 0, stream>>>(h, W, w1, w2, Wh16, s1, s2);
    k_scanA_part<<<SCANA_NB, 256, 0, stream>>>(hist_t, bsum);
    k_scanA_mid<<<1, 256, 0, stream>>>(bsum);
    k_scanA_final<<<SCANA_NB, 256, 0, stream>>>(hist_t, bsum, flat_scan);
    k_binA<<<NBLK, 256, 0, stream>>>(ei, s1, s2, flat_scan, brec, ae_orig);
    k_fine<<<NB, 256, 0, stream>>>(brec, flat_scan, offsets, sa_sorted);
    k_agg<<<(N_NODES * 64 + 255) / 256, 256, 0, stream>>>(sa_sorted, offsets, Wh16,
                                                          out, inv_tab);
    k_norm<<<(N_EDGES / 4 + 255) / 256, 256, 0, stream>>>(ei + N_EDGES, ae_orig,
                                                          inv_tab, alpha_norm);
}